// Round 12
// baseline (277.748 us; speedup 1.0000x reference)
//
#include <hip/hip_runtime.h>

#define N_NODES 50000
#define N_EDGES 600000
#define IN_DIM 256
#define HID 128
#define OUT_DIM 10
#define BN_EPS 1e-5f
#define CAP 64                      // bucket capacity (max deg; Poisson(12) -> ~40 max)

typedef unsigned int uint32;
typedef unsigned short ushort_t;
typedef __attribute__((ext_vector_type(8))) short short8;   // 8 bf16 = 4 VGPRs
typedef __attribute__((ext_vector_type(4))) float float4v;  // MFMA acc

__device__ __forceinline__ unsigned short f2bf_rne(float f) {
    uint32 u = __float_as_uint(f);
    u += 0x7FFF + ((u >> 16) & 1);          // round-to-nearest-even
    return (unsigned short)(u >> 16);
}
__device__ __forceinline__ float bf_lo(uint32 v) { return __uint_as_float(v << 16); }
__device__ __forceinline__ float bf_hi(uint32 v) { return __uint_as_float(v & 0xFFFF0000u); }
__device__ __forceinline__ float bfs(unsigned short s) { return __uint_as_float((uint32)s << 16); }

// ---------------- dispatch 1: zero(cntf+colsum) || weight pack ----------------
// zero span: cntf (200192B padded) + colsumAll (98304B) = 298496B = 18656 uint4
#define ZERO_UINT4 18656
#define ZERO_BLK 73
// pack layout: P[((kt*8+nt)*64+lane)*8+j] = bf16( W[kt*32+(lane>>4)*8+j][nt*16+(lane&15)] )

__global__ __launch_bounds__(256) void zero_pack_kernel(uint4* __restrict__ zbase,
                                                        const float* __restrict__ W_in,
                                                        const float* __restrict__ Wc,
                                                        unsigned short* __restrict__ PWin,
                                                        unsigned short* __restrict__ PWc) {
    if (blockIdx.x < ZERO_BLK) {
        int i = blockIdx.x * 256 + threadIdx.x;
        if (i < ZERO_UINT4) {
            uint4 z; z.x = 0; z.y = 0; z.z = 0; z.w = 0;
            zbase[i] = z;
        }
        return;
    }
    int idx = (blockIdx.x - ZERO_BLK) * 256 + threadIdx.x;
    if (idx >= 4096 + 3 * 2048) return;
    const float* W;
    unsigned short* P;
    int r;
    if (idx < 4096) { W = W_in; P = PWin + (size_t)idx * 8; r = idx; }
    else {
        int t = idx - 4096;
        int layer = t / 2048;
        r = t - layer * 2048;
        W = Wc + (size_t)layer * HID * HID;
        P = PWc + (size_t)(layer * 2048 + r) * 8;
    }
    int lane = r & 63;
    int nt = (r >> 6) & 7;
    int kt = r >> 9;
    int n = nt * 16 + (lane & 15);
    int kbase = kt * 32 + (lane >> 4) * 8;
    #pragma unroll
    for (int j = 0; j < 8; ++j) P[j] = f2bf_rne(W[(size_t)(kbase + j) * HID + n]);
}

// ---------------- dispatch 2: bucket-fill || input GEMM (BM=32), role-interleaved ----------------
// fill: each thread owns 4 consecutive edges (int4 loads of dst/src), 4 independent
// atomics + 4 scatter stores. NO fences (R3 lesson).
// gemm: h0 = relu(x@W_in + b_in); B16 = h0 @ Wc0 (UNSCALED -- fill concurrent).
// R12: M-tile 64 -> 32 rows. R10 falsified LDS-capped occupancy; counters say the
// dispatch is GRID-limited (782 gemm blocks ~3/CU, Occ 20%). 32-row tiles double the
// block count (1563 gemm blocks, grid 2149 ~8.4/CU) and halve per-block latency.
// Wave decomp: wr=w&1 row-half (16 rows), wc=w>>1 col-half (4 nt); per-output MFMA
// order unchanged -> bit-identical numerics. As 16.9KB; Hs overlays As.

#define FILL_BLK 586   // 586*256 = 150016 threads >= 150000 (4 edges each)
#define GBLK32 1563    // ceil(50000/32)
// grid = 586 + 1563 = 2149. evens (1075) -> gemm gid 0..1074;
// odds f=bid>>1: f<586 -> fill(f); f in [586,1074) -> gemm gid = 1075+(f-586).

__global__ __launch_bounds__(256) void fill_gemm_in(const int* __restrict__ src,
                                                    const int* __restrict__ dst,
                                                    float* __restrict__ cntf,
                                                    ushort_t* __restrict__ col,
                                                    const float* __restrict__ x,
                                                    const unsigned short* __restrict__ PWin,
                                                    const unsigned short* __restrict__ PWc0,
                                                    const float* __restrict__ b_in,
                                                    unsigned short* __restrict__ B16, int M) {
    __shared__ unsigned short As[32 * 264];    // x tile bf16; Hs overlays after kt-loop
    unsigned short* Hs = As;                   // 32*136 overlay (As is dead by then)
    int tid = threadIdx.x;

    int bid = blockIdx.x;
    int gid;
    if ((bid & 1) == 0) {
        gid = bid >> 1;                        // even -> gemm 0..1074
    } else {
        int f = bid >> 1;
        if (f < FILL_BLK) {                    // odd, first 586 -> fill
            int e0 = (f * 256 + tid) * 4;
            if (e0 < N_EDGES) {                // N_EDGES % 4 == 0, full int4 always
                int4 d4 = *(const int4*)(dst + e0);
                int4 s4 = *(const int4*)(src + e0);
                int p0 = (int)atomicAdd(&cntf[d4.x], 1.0f);
                int p1 = (int)atomicAdd(&cntf[d4.y], 1.0f);
                int p2 = (int)atomicAdd(&cntf[d4.z], 1.0f);
                int p3 = (int)atomicAdd(&cntf[d4.w], 1.0f);
                if (p0 < CAP) col[(size_t)d4.x * CAP + p0] = (ushort_t)s4.x;
                if (p1 < CAP) col[(size_t)d4.y * CAP + p1] = (ushort_t)s4.y;
                if (p2 < CAP) col[(size_t)d4.z * CAP + p2] = (ushort_t)s4.z;
                if (p3 < CAP) col[(size_t)d4.w * CAP + p3] = (ushort_t)s4.w;
            }
            return;
        }
        gid = 1075 + (f - FILL_BLK);           // odd tail -> gemm 1075..1562
    }

    int w = tid >> 6, lane = tid & 63;
    int mrow = lane & 15, quad = lane >> 4;
    int wr = w & 1;          // row half: rows wr*16..+15
    int wc = w >> 1;         // col half: nt group wc*4..+3
    int m0 = gid * 32;

    int r = tid >> 3;        // staging row 0..31
    int c8 = tid & 7;        // 32-col chunk
    int row = m0 + r;

    // stage the whole 32x256 x-tile as bf16 (one barrier)
    if (row < M) {
        const float* xr = x + (size_t)row * IN_DIM + c8 * 32;
        #pragma unroll
        for (int c = 0; c < 4; ++c) {
            const float* srcp = xr + c * 8;
            float4 a0 = *(const float4*)(srcp);
            float4 a1 = *(const float4*)(srcp + 4);
            short8 pk;
            pk[0] = (short)f2bf_rne(a0.x); pk[1] = (short)f2bf_rne(a0.y);
            pk[2] = (short)f2bf_rne(a0.z); pk[3] = (short)f2bf_rne(a0.w);
            pk[4] = (short)f2bf_rne(a1.x); pk[5] = (short)f2bf_rne(a1.y);
            pk[6] = (short)f2bf_rne(a1.z); pk[7] = (short)f2bf_rne(a1.w);
            *(short8*)&As[r * 264 + c8 * 32 + c * 8] = pk;
        }
    } else {
        short8 z;
        #pragma unroll
        for (int j = 0; j < 8; ++j) z[j] = 0;
        #pragma unroll
        for (int c = 0; c < 4; ++c) *(short8*)&As[r * 264 + c8 * 32 + c * 8] = z;
    }
    __syncthreads();

    float4v acc[4];
    #pragma unroll
    for (int nt = 0; nt < 4; ++nt)
        #pragma unroll
        for (int i = 0; i < 4; ++i) acc[nt][i] = 0.f;

    #pragma unroll
    for (int kt = 0; kt < 8; ++kt) {
        short8 afrag = *(const short8*)&As[(wr * 16 + mrow) * 264 + kt * 32 + quad * 8];
        #pragma unroll
        for (int nt = 0; nt < 4; ++nt) {
            int ntg = wc * 4 + nt;
            const unsigned short* pb = PWin + ((size_t)(kt * 8 + ntg) * 64 + lane) * 8;
            short8 bfrag = *(const short8*)(pb);
            acc[nt] = __builtin_amdgcn_mfma_f32_16x16x32_bf16(afrag, bfrag, acc[nt], 0, 0, 0);
        }
    }
    __syncthreads();         // As dead from here; Hs overlay becomes writable

    // epilogue-1: h0 = relu(acc + b_in) -> Hs (D-layout: row=wr*16+quad*4+reg, col=ntg*16+mrow)
    int rl = wr * 16 + quad * 4;
    #pragma unroll
    for (int nt = 0; nt < 4; ++nt) {
        int col_ = (wc * 4 + nt) * 16 + mrow;
        float bv = b_in[col_];
        #pragma unroll
        for (int reg = 0; reg < 4; ++reg) {
            float h = fmaxf(acc[nt][reg] + bv, 0.f);
            Hs[(rl + reg) * 136 + col_] = f2bf_rne(h);
        }
    }
    __syncthreads();

    // second GEMM: B = h0 @ Wc0 (K=128 from Hs)
    float4v acc2[4];
    #pragma unroll
    for (int nt = 0; nt < 4; ++nt)
        #pragma unroll
        for (int i = 0; i < 4; ++i) acc2[nt][i] = 0.f;

    #pragma unroll
    for (int kt = 0; kt < 4; ++kt) {
        short8 af2 = *(const short8*)&Hs[(wr * 16 + mrow) * 136 + kt * 32 + quad * 8];
        #pragma unroll
        for (int nt = 0; nt < 4; ++nt) {
            int ntg = wc * 4 + nt;
            const unsigned short* pb = PWc0 + ((size_t)(kt * 8 + ntg) * 64 + lane) * 8;
            short8 bfrag = *(const short8*)(pb);
            acc2[nt] = __builtin_amdgcn_mfma_f32_16x16x32_bf16(af2, bfrag, acc2[nt], 0, 0, 0);
        }
    }

    // epilogue-2: B16 = acc2 (unscaled)
    int rowbase = m0 + wr * 16 + quad * 4;
    #pragma unroll
    for (int nt = 0; nt < 4; ++nt) {
        int col_ = (wc * 4 + nt) * 16 + mrow;
        #pragma unroll
        for (int reg = 0; reg < 4; ++reg) {
            int rw = rowbase + reg;
            if (rw < M) B16[(size_t)rw * HID + col_] = f2bf_rne(acc2[nt][reg]);
        }
    }
}

// ---------------- fused bucket aggregation + BN column stats (C out = bf16) ----------------
// One node per wave; lanes 0-31 even edges, 32-63 odd edges, uint2 gathers. Bucket ids via
// 2 broadcast uint4 loads + bit-extract. NO fences (R3 lesson).
// template PRE: PRE=0 (layer 0) -- messages unscaled, per-edge wk = rsqrt(cnt[src]+1)
// gathered from cntf; PRE=1 (layers 1,2) -- messages PRE-SCALED by dinv[src] in the
// producing GEMM's epilogue (GCN linearity): pure gather-sum.
// Self term: C = dn*(sum B' + B'_n) = dn*sum + dn^2*B_n.

template <int PRE>
__global__ __launch_bounds__(256) void agg_stats_kernel(const uint32* __restrict__ Bs32,  // [N][64]
                                                        const float* __restrict__ cntf,
                                                        const ushort_t* __restrict__ col,  // [N][CAP]
                                                        const float* __restrict__ bc,
                                                        uint32* __restrict__ C16,          // [N][64]
                                                        float* __restrict__ colsum_multi) { // [32][256]
    __shared__ float shs[4][128];
    __shared__ float shq[4][128];
    int lane = threadIdx.x;            // 0..63
    int ty = threadIdx.y;              // 0..3
    int n = blockIdx.x * 4 + ty;       // N_NODES % 4 == 0
    int h = lane >> 5;                 // edge parity served by this lane
    int c = lane & 31;                 // uint2 column -> features 4c..4c+3
    int sh = h << 4;                   // 0 or 16

    const uint2* B2 = (const uint2*)Bs32;   // [N][32]
    float cn = cntf[n];
    int deg = (int)cn;
    if (deg > CAP) deg = CAP;
    float dn = rsqrtf(cn + 1.0f);

    float a0 = 0.f, a1 = 0.f, a2 = 0.f, a3 = 0.f;
    if (h == 0) {                           // self term
        uint2 vs = B2[(size_t)n * 32 + c];
        if (PRE) {                          // B'_n = dn*B_n; final *dn gives dn^2*B_n
            a0 = bf_lo(vs.x); a1 = bf_hi(vs.x);
            a2 = bf_lo(vs.y); a3 = bf_hi(vs.y);
        } else {                            // weight dn (squared by final *dn)
            a0 = dn * bf_lo(vs.x); a1 = dn * bf_hi(vs.x);
            a2 = dn * bf_lo(vs.y); a3 = dn * bf_hi(vs.y);
        }
    }

    const uint4* cb = (const uint4*)(col + (size_t)n * CAP);  // 8 bucket uint4s
    int e = 0;
    for (; e + 16 <= deg; e += 16) {        // full 16-edge batches, no masks
        uint4 q0 = cb[e >> 3];
        uint4 q1 = cb[(e >> 3) + 1];
        int s[8];
        s[0] = (q0.x >> sh) & 0xFFFF; s[1] = (q0.y >> sh) & 0xFFFF;
        s[2] = (q0.z >> sh) & 0xFFFF; s[3] = (q0.w >> sh) & 0xFFFF;
        s[4] = (q1.x >> sh) & 0xFFFF; s[5] = (q1.y >> sh) & 0xFFFF;
        s[6] = (q1.z >> sh) & 0xFFFF; s[7] = (q1.w >> sh) & 0xFFFF;
        float cg[8];
        if (!PRE) {
            #pragma unroll
            for (int k = 0; k < 8; ++k) cg[k] = cntf[s[k]];
        }
        uint2 v[8];
        #pragma unroll
        for (int k = 0; k < 8; ++k) v[k] = B2[(size_t)s[k] * 32 + c];
        #pragma unroll
        for (int k = 0; k < 8; ++k) {
            if (PRE) {
                a0 += bf_lo(v[k].x); a1 += bf_hi(v[k].x);
                a2 += bf_lo(v[k].y); a3 += bf_hi(v[k].y);
            } else {
                float wk = rsqrtf(cg[k] + 1.0f);
                a0 += wk * bf_lo(v[k].x); a1 += wk * bf_hi(v[k].x);
                a2 += wk * bf_lo(v[k].y); a3 += wk * bf_hi(v[k].y);
            }
        }
    }
    if (e < deg) {                          // masked tail, 1..15 edges
        uint4 q0 = cb[e >> 3];
        uint4 q1 = cb[(e >> 3) + 1];
        int rem = deg - e;
        int sfirst = (int)(q0.x & 0xFFFFu); // first remaining edge (always valid)
        uint32 dw[8] = {q0.x, q0.y, q0.z, q0.w, q1.x, q1.y, q1.z, q1.w};
        int s[8]; float msk[8];
        #pragma unroll
        for (int k = 0; k < 8; ++k) {
            int valid = (2 * k + h) < rem;
            s[k] = valid ? (int)((dw[k] >> sh) & 0xFFFFu) : sfirst;
            msk[k] = valid ? 1.f : 0.f;
        }
        float cg[8];
        if (!PRE) {
            #pragma unroll
            for (int k = 0; k < 8; ++k) cg[k] = cntf[s[k]];
        }
        uint2 v[8];
        #pragma unroll
        for (int k = 0; k < 8; ++k) v[k] = B2[(size_t)s[k] * 32 + c];
        #pragma unroll
        for (int k = 0; k < 8; ++k) {
            float wk = PRE ? msk[k] : (msk[k] * rsqrtf(cg[k] + 1.0f));
            a0 += wk * bf_lo(v[k].x); a1 += wk * bf_hi(v[k].x);
            a2 += wk * bf_lo(v[k].y); a3 += wk * bf_hi(v[k].y);
        }
    }

    // combine the two edge-parity halves
    a0 += __shfl_xor(a0, 32, 64);
    a1 += __shfl_xor(a1, 32, 64);
    a2 += __shfl_xor(a2, 32, 64);
    a3 += __shfl_xor(a3, 32, 64);

    float4 bcv = *(const float4*)(bc + c * 4);
    float o0 = a0 * dn + bcv.x;
    float o1 = a1 * dn + bcv.y;
    float o2 = a2 * dn + bcv.z;
    float o3 = a3 * dn + bcv.w;

    // each lane emits 2 of its 4 features: h=0 -> (4c,4c+1), h=1 -> (4c+2,4c+3)
    float e0 = h ? o2 : o0;
    float e1 = h ? o3 : o1;
    C16[(size_t)n * 64 + c * 2 + h] = (uint32)f2bf_rne(e0) | ((uint32)f2bf_rne(e1) << 16);

    int f = c * 4 + h * 2;
    shs[ty][f] = e0;       shs[ty][f + 1] = e1;
    shq[ty][f] = e0 * e0;  shq[ty][f + 1] = e1 * e1;
    __syncthreads();
    int t = ty * 64 + lane;            // 0..255
    if (t < 128) {
        float s = shs[0][t] + shs[1][t] + shs[2][t] + shs[3][t];
        float q = shq[0][t] + shq[1][t] + shq[2][t] + shq[3][t];
        float* base = colsum_multi + (size_t)(blockIdx.x & 31) * 256;
        atomicAdd(&base[t], s);
        atomicAdd(&base[t + 128], q);
    }
}

// ---------------- fused BN-finalize + BN-apply + residual + next message GEMM (BM=32) ----------------
// Prologue re-sums the 32 hashed colsum copies (plain loads; kernel boundary gives
// coherence). Register-staged C16/A16, 32x136 LDS tile, 2 barriers, 16 MFMAs/wave.
// R12: 32-row tiles (1563 blocks, was 782) -- same grid-limitation fix as fill_gemm_in.
// B16 = (h@Wc) * dinv[row] -- PRE-SCALED for the next agg (counts final here).

template <int RES>
__global__ __launch_bounds__(256) void gemm_bn_fused(const unsigned short* __restrict__ C16,
                                                     const unsigned short* __restrict__ PB,
                                                     const float* __restrict__ colsum_multi,
                                                     const float* __restrict__ gamma,
                                                     const float* __restrict__ beta,
                                                     const float* __restrict__ cntf,
                                                     unsigned short* __restrict__ A16,
                                                     unsigned short* __restrict__ B16, int M) {
    __shared__ unsigned short As[32 * 136];
    __shared__ float scs[128], shb[128];
    int tid = threadIdx.x;
    int w = tid >> 6, lane = tid & 63;
    int mrow = lane & 15, quad = lane >> 4;
    int wr = w & 1;          // row half
    int wc = w >> 1;         // col half (nt group)
    int m0 = blockIdx.x * 32;

    if (tid < 128) {                       // in-block BN finalize
        float s = 0.f, q = 0.f;
        #pragma unroll
        for (int cc = 0; cc < 32; ++cc) {
            s += colsum_multi[cc * 256 + tid];
            q += colsum_multi[cc * 256 + tid + 128];
        }
        float mu = s * (1.0f / N_NODES);
        float var = q * (1.0f / N_NODES) - mu * mu;
        float rstd = rsqrtf(var + BN_EPS);
        float sc = rstd * gamma[tid];
        scs[tid] = sc;
        shb[tid] = beta[tid] - mu * sc;
    }

    int r = tid >> 3;        // 0..31
    int c8 = tid & 7;        // 16-col chunk
    int row = m0 + r;
    bool vrow = row < M;
    short8 cv[2], av[2];
    if (vrow) {
        #pragma unroll
        for (int u = 0; u < 2; ++u)
            cv[u] = *(const short8*)(C16 + (size_t)row * HID + c8 * 16 + u * 8);
        if (RES) {
            #pragma unroll
            for (int u = 0; u < 2; ++u)
                av[u] = *(const short8*)(A16 + (size_t)row * HID + c8 * 16 + u * 8);
        }
    }
    __syncthreads();

    if (vrow) {
        #pragma unroll
        for (int u = 0; u < 2; ++u) {
            int col0 = c8 * 16 + u * 8;
            short8 pk;
            #pragma unroll
            for (int j = 0; j < 8; ++j) {
                float h = fmaxf(bfs((unsigned short)cv[u][j]) * scs[col0 + j] + shb[col0 + j], 0.f);
                if (RES) h += bfs((unsigned short)av[u][j]);
                pk[j] = (short)f2bf_rne(h);
            }
            *(short8*)(A16 + (size_t)row * HID + col0) = pk;
            *(short8*)&As[r * 136 + col0] = pk;
        }
    } else {
        short8 z;
        #pragma unroll
        for (int j = 0; j < 8; ++j) z[j] = 0;
        #pragma unroll
        for (int u = 0; u < 2; ++u) *(short8*)&As[r * 136 + c8 * 16 + u * 8] = z;
    }
    __syncthreads();

    float4v acc[4];
    #pragma unroll
    for (int nt = 0; nt < 4; ++nt)
        #pragma unroll
        for (int i = 0; i < 4; ++i) acc[nt][i] = 0.f;

    #pragma unroll
    for (int kt = 0; kt < 4; ++kt) {
        short8 afrag = *(const short8*)&As[(wr * 16 + mrow) * 136 + kt * 32 + quad * 8];
        #pragma unroll
        for (int nt = 0; nt < 4; ++nt) {
            int ntg = wc * 4 + nt;
            const unsigned short* pb = PB + ((size_t)(kt * 8 + ntg) * 64 + lane) * 8;
            short8 bfrag = *(const short8*)(pb);
            acc[nt] = __builtin_amdgcn_mfma_f32_16x16x32_bf16(afrag, bfrag, acc[nt], 0, 0, 0);
        }
    }

    int rowbase = m0 + wr * 16 + quad * 4;
    float rs[4];
    #pragma unroll
    for (int reg = 0; reg < 4; ++reg) {
        int rw = rowbase + reg;
        rs[reg] = (rw < M) ? rsqrtf(cntf[rw] + 1.0f) : 0.f;   // dinv[row] pre-scale
    }
    #pragma unroll
    for (int nt = 0; nt < 4; ++nt) {
        int col = (wc * 4 + nt) * 16 + mrow;
        #pragma unroll
        for (int reg = 0; reg < 4; ++reg) {
            int rw = rowbase + reg;
            if (rw < M) B16[(size_t)rw * HID + col] = f2bf_rne(acc[nt][reg] * rs[reg]);
        }
    }
}

// ---------------- fused final BN-finalize+apply + output projection ----------------
// h3 = relu(bf16(C)*sc+sh) + A16 (LDS only); out = h3 @ Wo + bo.
// Wo transposed into WoT[c][k]; inner product reads Hs and WoT as float4.

__global__ void out_fused(const uint32* __restrict__ C16,  // [N][64]
                          const uint32* __restrict__ A16,  // [N][64]
                          const float* __restrict__ colsum_multi,
                          const float* __restrict__ gamma,
                          const float* __restrict__ beta,
                          const float* __restrict__ Wo,
                          const float* __restrict__ bo,
                          float* __restrict__ out) {
    __shared__ float Hs[64][132];          // pad 4
    __shared__ float WoT[OUT_DIM][132];    // transposed Wo, pad 4
    __shared__ float scs[128], shb[128];
    int tid = threadIdx.x;
    for (int i = tid; i < HID * OUT_DIM; i += 256) {
        int k = i / OUT_DIM;
        int c = i - k * OUT_DIM;
        WoT[c][k] = Wo[i];                 // coalesced Wo read
    }
    if (tid < 128) {
        float s = 0.f, q = 0.f;
        #pragma unroll
        for (int cc = 0; cc < 32; ++cc) {
            s += colsum_multi[cc * 256 + tid];
            q += colsum_multi[cc * 256 + tid + 128];
        }
        float mu = s * (1.0f / N_NODES);
        float var = q * (1.0f / N_NODES) - mu * mu;
        float rstd = rsqrtf(var + BN_EPS);
        float sc = rstd * gamma[tid];
        scs[tid] = sc;
        shb[tid] = beta[tid] - mu * sc;
    }
    __syncthreads();

    int n0 = blockIdx.x * 64;
    #pragma unroll
    for (int i = 0; i < 8; ++i) {
        int lin = i * 256 + tid;           // 0..2047
        int row = lin >> 5;                // 0..63
        int colq = lin & 31;               // 4-feature group
        int n = n0 + row;
        float4 h = make_float4(0.f, 0.f, 0.f, 0.f);
        if (n < N_NODES) {
            uint2 cv = ((const uint2*)C16)[(size_t)n * 32 + colq];
            uint2 av = ((const uint2*)A16)[(size_t)n * 32 + colq];
            float c0 = bf_lo(cv.x), c1 = bf_hi(cv.x), c2 = bf_lo(cv.y), c3 = bf_hi(cv.y);
            float4 s = *(const float4*)(scs + colq * 4);
            float4 t = *(const float4*)(shb + colq * 4);
            h.x = fmaxf(c0 * s.x + t.x, 0.f) + bf_lo(av.x);
            h.y = fmaxf(c1 * s.y + t.y, 0.f) + bf_hi(av.x);
            h.z = fmaxf(c2 * s.z + t.z, 0.f) + bf_lo(av.y);
            h.w = fmaxf(c3 * s.w + t.w, 0.f) + bf_hi(av.y);
        }
        *(float4*)&Hs[row][colq * 4] = h;
    }
    __syncthreads();

    #pragma unroll
    for (int j = 0; j < 3; ++j) {
        int o = j * 256 + tid;             // 0..639
        if (o < 64 * OUT_DIM) {
            int nl = o / OUT_DIM;
            int c = o - nl * OUT_DIM;
            int n = n0 + nl;
            if (n < N_NODES) {
                float s = 0.f;
                #pragma unroll 8
                for (int k = 0; k < HID; k += 4) {
                    float4 hv = *(const float4*)&Hs[nl][k];
                    float4 wv = *(const float4*)&WoT[c][k];
                    s += hv.x * wv.x;      // same order as scalar loop: bit-identical
                    s += hv.y * wv.y;
                    s += hv.z * wv.z;
                    s += hv.w * wv.w;
                }
                out[(size_t)n * OUT_DIM + c] = s + bo[c];
            }
        }
    }
}

// ---------------- launch ----------------

extern "C" void kernel_launch(void* const* d_in, const int* in_sizes, int n_in,
                              void* d_out, int out_size, void* d_ws, size_t ws_size,
                              hipStream_t stream) {
    const float* x     = (const float*)d_in[0];
    const int*   ei    = (const int*)d_in[1];
    const int*   src   = ei;
    const int*   dst   = ei + N_EDGES;
    const float* W_in  = (const float*)d_in[2];
    const float* b_in  = (const float*)d_in[3];
    const float* Wc    = (const float*)d_in[4];
    const float* bc    = (const float*)d_in[5];
    const float* gamma = (const float*)d_in[6];
    const float* beta  = (const float*)d_in[7];
    const float* W_out = (const float*)d_in[8];
    const float* b_out = (const float*)d_in[9];
    float* out = (float*)d_out;

    char* p = (char*)d_ws;
    auto alloc = [&](size_t bytes) -> char* {
        char* q = p;
        p += (bytes + 255) & ~(size_t)255;
        return q;
    };
    // zero span: cntf (200192B) + colsumAll (98304B) = 298496B
    float* cntf      = (float*)alloc(sizeof(float) * N_NODES);               // float edge counts
    float* colsumAll = (float*)alloc(sizeof(float) * 3 * 32 * 256);          // 32 hashed copies per layer
    unsigned short* A16 = (unsigned short*)alloc(sizeof(unsigned short) * N_NODES * HID); // residual h bf16
    unsigned short* B16 = (unsigned short*)alloc(sizeof(unsigned short) * N_NODES * HID); // messages bf16
    uint32* C16       = (uint32*)alloc(sizeof(unsigned short) * N_NODES * HID);           // aggregated bf16
    ushort_t* col     = (ushort_t*)alloc(sizeof(ushort_t) * N_NODES * CAP);  // bucketed src ids
    unsigned short* PWin = (unsigned short*)alloc(sizeof(unsigned short) * 4096 * 8);
    unsigned short* PWc  = (unsigned short*)alloc(sizeof(unsigned short) * 3 * 2048 * 8);

    // 1: zero (cntf+colsum) || pack all weights
    zero_pack_kernel<<<ZERO_BLK + 40, 256, 0, stream>>>((uint4*)cntf, W_in, Wc, PWin, PWc);

    // 2: bucket-fill || input GEMM (BM=32, 1563 gemm blocks), role-interleaved
    fill_gemm_in<<<FILL_BLK + GBLK32, 256, 0, stream>>>(src, dst, cntf, col,
                                                        x, PWin, PWc, b_in, B16, N_NODES);

    const int oblk = (N_NODES + 63) / 64;   // 782 (out_fused keeps 64-row tiles)

    for (int l = 0; l < 3; ++l) {
        float* colsum = colsumAll + (size_t)l * 32 * 256;
        if (l == 0) {
            agg_stats_kernel<0><<<N_NODES / 4, dim3(64, 4), 0, stream>>>(
                (const uint32*)B16, cntf, col, bc + l * HID, C16, colsum);
        } else {
            agg_stats_kernel<1><<<N_NODES / 4, dim3(64, 4), 0, stream>>>(
                (const uint32*)B16, cntf, col, bc + l * HID, C16, colsum);
        }
        if (l == 0) {
            gemm_bn_fused<0><<<GBLK32, 256, 0, stream>>>(
                (const unsigned short*)C16, PWc + (size_t)1 * 2048 * 8, colsum,
                gamma, beta, cntf, A16, B16, N_NODES);
        } else if (l == 1) {
            gemm_bn_fused<1><<<GBLK32, 256, 0, stream>>>(
                (const unsigned short*)C16, PWc + (size_t)2 * 2048 * 8, colsum,
                gamma + HID, beta + HID, cntf, A16, B16, N_NODES);
        } else {
            out_fused<<<oblk, 256, 0, stream>>>(
                C16, (const uint32*)A16, colsum, gamma + 2 * HID, beta + 2 * HID, W_out, b_out, out);
        }
    }
}

// Round 13
// 275.310 us; speedup vs baseline: 1.0089x; 1.0089x over previous
//
#include <hip/hip_runtime.h>

#define N_NODES 50000
#define N_EDGES 600000
#define IN_DIM 256
#define HID 128
#define OUT_DIM 10
#define BN_EPS 1e-5f
#define CAP 64                      // bucket capacity (max deg; Poisson(12) -> ~40 max)

typedef unsigned int uint32;
typedef unsigned short ushort_t;
typedef __attribute__((ext_vector_type(8))) short short8;   // 8 bf16 = 4 VGPRs
typedef __attribute__((ext_vector_type(4))) float float4v;  // MFMA acc

__device__ __forceinline__ unsigned short f2bf_rne(float f) {
    uint32 u = __float_as_uint(f);
    u += 0x7FFF + ((u >> 16) & 1);          // round-to-nearest-even
    return (unsigned short)(u >> 16);
}
__device__ __forceinline__ float bf_lo(uint32 v) { return __uint_as_float(v << 16); }
__device__ __forceinline__ float bf_hi(uint32 v) { return __uint_as_float(v & 0xFFFF0000u); }
__device__ __forceinline__ float bfs(unsigned short s) { return __uint_as_float((uint32)s << 16); }

// ---------------- dispatch 1: zero(cntf+colsum) || weight pack ----------------
// zero span: cntf (200192B padded) + colsumAll (98304B) = 298496B = 18656 uint4
#define ZERO_UINT4 18656
#define ZERO_BLK 73
// pack layout: P[((kt*8+nt)*64+lane)*8+j] = bf16( W[kt*32+(lane>>4)*8+j][nt*16+(lane&15)] )

__global__ __launch_bounds__(256) void zero_pack_kernel(uint4* __restrict__ zbase,
                                                        const float* __restrict__ W_in,
                                                        const float* __restrict__ Wc,
                                                        unsigned short* __restrict__ PWin,
                                                        unsigned short* __restrict__ PWc) {
    if (blockIdx.x < ZERO_BLK) {
        int i = blockIdx.x * 256 + threadIdx.x;
        if (i < ZERO_UINT4) {
            uint4 z; z.x = 0; z.y = 0; z.z = 0; z.w = 0;
            zbase[i] = z;
        }
        return;
    }
    int idx = (blockIdx.x - ZERO_BLK) * 256 + threadIdx.x;
    if (idx >= 4096 + 3 * 2048) return;
    const float* W;
    unsigned short* P;
    int r;
    if (idx < 4096) { W = W_in; P = PWin + (size_t)idx * 8; r = idx; }
    else {
        int t = idx - 4096;
        int layer = t / 2048;
        r = t - layer * 2048;
        W = Wc + (size_t)layer * HID * HID;
        P = PWc + (size_t)(layer * 2048 + r) * 8;
    }
    int lane = r & 63;
    int nt = (r >> 6) & 7;
    int kt = r >> 9;
    int n = nt * 16 + (lane & 15);
    int kbase = kt * 32 + (lane >> 4) * 8;
    #pragma unroll
    for (int j = 0; j < 8; ++j) P[j] = f2bf_rne(W[(size_t)(kbase + j) * HID + n]);
}

// ---------------- dispatch 2: bucket-fill || input GEMM, role-interleaved ----------------
// fill: each thread owns 4 consecutive edges (int4 loads of dst/src), 4 independent
// atomics + 4 scatter stores. NO fences (R3 lesson).
// gemm: h0 = relu(x@W_in + b_in); B16 = h0 @ Wc0 (UNSCALED -- fill concurrent).
// R13 (final): R6/R11-proven config. Ledger: tile 64<->32 (R12: slower), LDS 51/34/17KB
// (R10: slower), occupancy 20<->40% (R12: no effect), staging fp32<->bf16 (R8: flat) all
// A/B-falsified -- d2's ~50us is the fill's scatter/atomic stream, not a gemm-side cost.
// Hs overlaid on As; roles interleaved by bid parity.

#define FILL_BLK 586   // 586*256 = 150016 threads >= 150000 (4 edges each)
// grid = FILL_BLK + gblk = 586 + 782 = 1368; evens (684) -> gemm 0..683;
// odds f=bid>>1: f<586 -> fill(f); f>=586 -> gemm(f+98) = 684..781.

__global__ __launch_bounds__(256) void fill_gemm_in(const int* __restrict__ src,
                                                    const int* __restrict__ dst,
                                                    float* __restrict__ cntf,
                                                    ushort_t* __restrict__ col,
                                                    const float* __restrict__ x,
                                                    const unsigned short* __restrict__ PWin,
                                                    const unsigned short* __restrict__ PWc0,
                                                    const float* __restrict__ b_in,
                                                    unsigned short* __restrict__ B16, int M) {
    __shared__ unsigned short As[64 * 264];    // x tile bf16; Hs overlays after kt-loop
    unsigned short* Hs = As;                   // 64*136 overlay (As is dead by then)
    int tid = threadIdx.x;

    int bid = blockIdx.x;
    int gid;
    if ((bid & 1) == 0) {
        gid = bid >> 1;                        // even -> gemm 0..683
    } else {
        int f = bid >> 1;
        if (f < FILL_BLK) {                    // odd, first 586 -> fill
            int e0 = (f * 256 + tid) * 4;
            if (e0 < N_EDGES) {                // N_EDGES % 4 == 0, full int4 always
                int4 d4 = *(const int4*)(dst + e0);
                int4 s4 = *(const int4*)(src + e0);
                int p0 = (int)atomicAdd(&cntf[d4.x], 1.0f);
                int p1 = (int)atomicAdd(&cntf[d4.y], 1.0f);
                int p2 = (int)atomicAdd(&cntf[d4.z], 1.0f);
                int p3 = (int)atomicAdd(&cntf[d4.w], 1.0f);
                if (p0 < CAP) col[(size_t)d4.x * CAP + p0] = (ushort_t)s4.x;
                if (p1 < CAP) col[(size_t)d4.y * CAP + p1] = (ushort_t)s4.y;
                if (p2 < CAP) col[(size_t)d4.z * CAP + p2] = (ushort_t)s4.z;
                if (p3 < CAP) col[(size_t)d4.w * CAP + p3] = (ushort_t)s4.w;
            }
            return;
        }
        gid = f + 98;                          // odd tail -> gemm 684..781
    }

    int w = tid >> 6, lane = tid & 63;
    int mrow = lane & 15, quad = lane >> 4;
    int m0 = gid * 64;

    int r = tid >> 2;        // staging row 0..63
    int cq = tid & 3;        // col quarter (8 floats within each 32-col chunk)
    int row = m0 + r;

    // stage the whole 64x256 x-tile as bf16 (one barrier)
    if (row < M) {
        const float* xr = x + (size_t)row * IN_DIM;
        #pragma unroll
        for (int c = 0; c < 8; ++c) {
            const float* srcp = xr + c * 32 + cq * 8;
            float4 a0 = *(const float4*)(srcp);
            float4 a1 = *(const float4*)(srcp + 4);
            short8 pk;
            pk[0] = (short)f2bf_rne(a0.x); pk[1] = (short)f2bf_rne(a0.y);
            pk[2] = (short)f2bf_rne(a0.z); pk[3] = (short)f2bf_rne(a0.w);
            pk[4] = (short)f2bf_rne(a1.x); pk[5] = (short)f2bf_rne(a1.y);
            pk[6] = (short)f2bf_rne(a1.z); pk[7] = (short)f2bf_rne(a1.w);
            *(short8*)&As[r * 264 + c * 32 + cq * 8] = pk;
        }
    } else {
        short8 z;
        #pragma unroll
        for (int j = 0; j < 8; ++j) z[j] = 0;
        #pragma unroll
        for (int c = 0; c < 8; ++c) *(short8*)&As[r * 264 + c * 32 + cq * 8] = z;
    }
    __syncthreads();

    float4v acc[8];
    #pragma unroll
    for (int nt = 0; nt < 8; ++nt)
        #pragma unroll
        for (int i = 0; i < 4; ++i) acc[nt][i] = 0.f;

    #pragma unroll
    for (int kt = 0; kt < 8; ++kt) {
        short8 afrag = *(const short8*)&As[(w * 16 + mrow) * 264 + kt * 32 + quad * 8];
        const unsigned short* pb = PWin + ((size_t)(kt * 8) * 64 + lane) * 8;
        #pragma unroll
        for (int nt = 0; nt < 8; ++nt) {
            short8 bfrag = *(const short8*)(pb + (size_t)nt * 64 * 8);
            acc[nt] = __builtin_amdgcn_mfma_f32_16x16x32_bf16(afrag, bfrag, acc[nt], 0, 0, 0);
        }
    }
    __syncthreads();         // As dead from here; Hs overlay becomes writable

    // epilogue-1: h0 = relu(acc + b_in) -> Hs (D-layout: row=w*16+quad*4+reg, col=nt*16+mrow)
    int rl = w * 16 + quad * 4;
    #pragma unroll
    for (int nt = 0; nt < 8; ++nt) {
        int col_ = nt * 16 + mrow;
        float bv = b_in[col_];
        #pragma unroll
        for (int reg = 0; reg < 4; ++reg) {
            float h = fmaxf(acc[nt][reg] + bv, 0.f);
            Hs[(rl + reg) * 136 + col_] = f2bf_rne(h);
        }
    }
    __syncthreads();

    // second GEMM: B = h0 @ Wc0 (K=128 from Hs)
    float4v acc2[8];
    #pragma unroll
    for (int nt = 0; nt < 8; ++nt)
        #pragma unroll
        for (int i = 0; i < 4; ++i) acc2[nt][i] = 0.f;

    #pragma unroll
    for (int kt = 0; kt < 4; ++kt) {
        short8 af2 = *(const short8*)&Hs[(w * 16 + mrow) * 136 + kt * 32 + quad * 8];
        const unsigned short* pb = PWc0 + ((size_t)(kt * 8) * 64 + lane) * 8;
        #pragma unroll
        for (int nt = 0; nt < 8; ++nt) {
            short8 bfrag = *(const short8*)(pb + (size_t)nt * 64 * 8);
            acc2[nt] = __builtin_amdgcn_mfma_f32_16x16x32_bf16(af2, bfrag, acc2[nt], 0, 0, 0);
        }
    }

    // epilogue-2: B16 = acc2 (unscaled)
    int rowbase = m0 + w * 16 + quad * 4;
    #pragma unroll
    for (int nt = 0; nt < 8; ++nt) {
        int col_ = nt * 16 + mrow;
        #pragma unroll
        for (int reg = 0; reg < 4; ++reg) {
            int rw = rowbase + reg;
            if (rw < M) B16[(size_t)rw * HID + col_] = f2bf_rne(acc2[nt][reg]);
        }
    }
}

// ---------------- fused bucket aggregation + BN column stats (C out = bf16) ----------------
// One node per wave; lanes 0-31 even edges, 32-63 odd edges, uint2 gathers. Bucket ids via
// 2 broadcast uint4 loads + bit-extract. NO fences (R3 lesson).
// template PRE: PRE=0 (layer 0) -- messages unscaled, per-edge wk = rsqrt(cnt[src]+1)
// gathered from cntf; PRE=1 (layers 1,2) -- messages PRE-SCALED by dinv[src] in the
// producing GEMM's epilogue (GCN linearity): pure gather-sum.
// Self term: C = dn*(sum B' + B'_n) = dn*sum + dn^2*B_n.

template <int PRE>
__global__ __launch_bounds__(256) void agg_stats_kernel(const uint32* __restrict__ Bs32,  // [N][64]
                                                        const float* __restrict__ cntf,
                                                        const ushort_t* __restrict__ col,  // [N][CAP]
                                                        const float* __restrict__ bc,
                                                        uint32* __restrict__ C16,          // [N][64]
                                                        float* __restrict__ colsum_multi) { // [32][256]
    __shared__ float shs[4][128];
    __shared__ float shq[4][128];
    int lane = threadIdx.x;            // 0..63
    int ty = threadIdx.y;              // 0..3
    int n = blockIdx.x * 4 + ty;       // N_NODES % 4 == 0
    int h = lane >> 5;                 // edge parity served by this lane
    int c = lane & 31;                 // uint2 column -> features 4c..4c+3
    int sh = h << 4;                   // 0 or 16

    const uint2* B2 = (const uint2*)Bs32;   // [N][32]
    float cn = cntf[n];
    int deg = (int)cn;
    if (deg > CAP) deg = CAP;
    float dn = rsqrtf(cn + 1.0f);

    float a0 = 0.f, a1 = 0.f, a2 = 0.f, a3 = 0.f;
    if (h == 0) {                           // self term
        uint2 vs = B2[(size_t)n * 32 + c];
        if (PRE) {                          // B'_n = dn*B_n; final *dn gives dn^2*B_n
            a0 = bf_lo(vs.x); a1 = bf_hi(vs.x);
            a2 = bf_lo(vs.y); a3 = bf_hi(vs.y);
        } else {                            // weight dn (squared by final *dn)
            a0 = dn * bf_lo(vs.x); a1 = dn * bf_hi(vs.x);
            a2 = dn * bf_lo(vs.y); a3 = dn * bf_hi(vs.y);
        }
    }

    const uint4* cb = (const uint4*)(col + (size_t)n * CAP);  // 8 bucket uint4s
    int e = 0;
    for (; e + 16 <= deg; e += 16) {        // full 16-edge batches, no masks
        uint4 q0 = cb[e >> 3];
        uint4 q1 = cb[(e >> 3) + 1];
        int s[8];
        s[0] = (q0.x >> sh) & 0xFFFF; s[1] = (q0.y >> sh) & 0xFFFF;
        s[2] = (q0.z >> sh) & 0xFFFF; s[3] = (q0.w >> sh) & 0xFFFF;
        s[4] = (q1.x >> sh) & 0xFFFF; s[5] = (q1.y >> sh) & 0xFFFF;
        s[6] = (q1.z >> sh) & 0xFFFF; s[7] = (q1.w >> sh) & 0xFFFF;
        float cg[8];
        if (!PRE) {
            #pragma unroll
            for (int k = 0; k < 8; ++k) cg[k] = cntf[s[k]];
        }
        uint2 v[8];
        #pragma unroll
        for (int k = 0; k < 8; ++k) v[k] = B2[(size_t)s[k] * 32 + c];
        #pragma unroll
        for (int k = 0; k < 8; ++k) {
            if (PRE) {
                a0 += bf_lo(v[k].x); a1 += bf_hi(v[k].x);
                a2 += bf_lo(v[k].y); a3 += bf_hi(v[k].y);
            } else {
                float wk = rsqrtf(cg[k] + 1.0f);
                a0 += wk * bf_lo(v[k].x); a1 += wk * bf_hi(v[k].x);
                a2 += wk * bf_lo(v[k].y); a3 += wk * bf_hi(v[k].y);
            }
        }
    }
    if (e < deg) {                          // masked tail, 1..15 edges
        uint4 q0 = cb[e >> 3];
        uint4 q1 = cb[(e >> 3) + 1];
        int rem = deg - e;
        int sfirst = (int)(q0.x & 0xFFFFu); // first remaining edge (always valid)
        uint32 dw[8] = {q0.x, q0.y, q0.z, q0.w, q1.x, q1.y, q1.z, q1.w};
        int s[8]; float msk[8];
        #pragma unroll
        for (int k = 0; k < 8; ++k) {
            int valid = (2 * k + h) < rem;
            s[k] = valid ? (int)((dw[k] >> sh) & 0xFFFFu) : sfirst;
            msk[k] = valid ? 1.f : 0.f;
        }
        float cg[8];
        if (!PRE) {
            #pragma unroll
            for (int k = 0; k < 8; ++k) cg[k] = cntf[s[k]];
        }
        uint2 v[8];
        #pragma unroll
        for (int k = 0; k < 8; ++k) v[k] = B2[(size_t)s[k] * 32 + c];
        #pragma unroll
        for (int k = 0; k < 8; ++k) {
            float wk = PRE ? msk[k] : (msk[k] * rsqrtf(cg[k] + 1.0f));
            a0 += wk * bf_lo(v[k].x); a1 += wk * bf_hi(v[k].x);
            a2 += wk * bf_lo(v[k].y); a3 += wk * bf_hi(v[k].y);
        }
    }

    // combine the two edge-parity halves
    a0 += __shfl_xor(a0, 32, 64);
    a1 += __shfl_xor(a1, 32, 64);
    a2 += __shfl_xor(a2, 32, 64);
    a3 += __shfl_xor(a3, 32, 64);

    float4 bcv = *(const float4*)(bc + c * 4);
    float o0 = a0 * dn + bcv.x;
    float o1 = a1 * dn + bcv.y;
    float o2 = a2 * dn + bcv.z;
    float o3 = a3 * dn + bcv.w;

    // each lane emits 2 of its 4 features: h=0 -> (4c,4c+1), h=1 -> (4c+2,4c+3)
    float e0 = h ? o2 : o0;
    float e1 = h ? o3 : o1;
    C16[(size_t)n * 64 + c * 2 + h] = (uint32)f2bf_rne(e0) | ((uint32)f2bf_rne(e1) << 16);

    int f = c * 4 + h * 2;
    shs[ty][f] = e0;       shs[ty][f + 1] = e1;
    shq[ty][f] = e0 * e0;  shq[ty][f + 1] = e1 * e1;
    __syncthreads();
    int t = ty * 64 + lane;            // 0..255
    if (t < 128) {
        float s = shs[0][t] + shs[1][t] + shs[2][t] + shs[3][t];
        float q = shq[0][t] + shq[1][t] + shq[2][t] + shq[3][t];
        float* base = colsum_multi + (size_t)(blockIdx.x & 31) * 256;
        atomicAdd(&base[t], s);
        atomicAdd(&base[t + 128], q);
    }
}

// ---------------- fused BN-finalize + BN-apply + residual + next message GEMM ----------------
// Prologue re-sums the 32 hashed colsum copies (plain loads; kernel boundary gives
// coherence -- validated R0-R2). Register-staged C16/A16, full 64x136 LDS tile,
// 2 barriers total, 32 MFMAs clustered.
// B16 = (h@Wc) * dinv[row] -- PRE-SCALED for the next agg (counts final here).

template <int RES>
__global__ __launch_bounds__(256) void gemm_bn_fused(const unsigned short* __restrict__ C16,
                                                     const unsigned short* __restrict__ PB,
                                                     const float* __restrict__ colsum_multi,
                                                     const float* __restrict__ gamma,
                                                     const float* __restrict__ beta,
                                                     const float* __restrict__ cntf,
                                                     unsigned short* __restrict__ A16,
                                                     unsigned short* __restrict__ B16, int M) {
    __shared__ unsigned short As[64 * 136];
    __shared__ float scs[128], shb[128];
    int tid = threadIdx.x;
    int w = tid >> 6, lane = tid & 63;
    int mrow = lane & 15, quad = lane >> 4;
    int m0 = blockIdx.x * 64;

    if (tid < 128) {                       // in-block BN finalize
        float s = 0.f, q = 0.f;
        #pragma unroll
        for (int cc = 0; cc < 32; ++cc) {
            s += colsum_multi[cc * 256 + tid];
            q += colsum_multi[cc * 256 + tid + 128];
        }
        float mu = s * (1.0f / N_NODES);
        float var = q * (1.0f / N_NODES) - mu * mu;
        float rstd = rsqrtf(var + BN_EPS);
        float sc = rstd * gamma[tid];
        scs[tid] = sc;
        shb[tid] = beta[tid] - mu * sc;
    }

    int r = tid >> 2;
    int cq = tid & 3;
    int row = m0 + r;
    bool vrow = row < M;
    short8 cv[4], av[4];
    if (vrow) {
        #pragma unroll
        for (int u = 0; u < 4; ++u)
            cv[u] = *(const short8*)(C16 + (size_t)row * HID + cq * 32 + u * 8);
        if (RES) {
            #pragma unroll
            for (int u = 0; u < 4; ++u)
                av[u] = *(const short8*)(A16 + (size_t)row * HID + cq * 32 + u * 8);
        }
    }
    __syncthreads();

    if (vrow) {
        #pragma unroll
        for (int u = 0; u < 4; ++u) {
            int col0 = cq * 32 + u * 8;
            short8 pk;
            #pragma unroll
            for (int j = 0; j < 8; ++j) {
                float h = fmaxf(bfs((unsigned short)cv[u][j]) * scs[col0 + j] + shb[col0 + j], 0.f);
                if (RES) h += bfs((unsigned short)av[u][j]);
                pk[j] = (short)f2bf_rne(h);
            }
            *(short8*)(A16 + (size_t)row * HID + col0) = pk;
            *(short8*)&As[r * 136 + col0] = pk;
        }
    } else {
        short8 z;
        #pragma unroll
        for (int j = 0; j < 8; ++j) z[j] = 0;
        #pragma unroll
        for (int u = 0; u < 4; ++u) *(short8*)&As[r * 136 + cq * 32 + u * 8] = z;
    }
    __syncthreads();

    float4v acc[8];
    #pragma unroll
    for (int nt = 0; nt < 8; ++nt)
        #pragma unroll
        for (int i = 0; i < 4; ++i) acc[nt][i] = 0.f;

    #pragma unroll
    for (int kt = 0; kt < 4; ++kt) {
        short8 afrag = *(const short8*)&As[(w * 16 + mrow) * 136 + kt * 32 + quad * 8];
        const unsigned short* pb = PB + ((size_t)(kt * 8) * 64 + lane) * 8;
        #pragma unroll
        for (int nt = 0; nt < 8; ++nt) {
            short8 bfrag = *(const short8*)(pb + (size_t)nt * 64 * 8);
            acc[nt] = __builtin_amdgcn_mfma_f32_16x16x32_bf16(afrag, bfrag, acc[nt], 0, 0, 0);
        }
    }

    int rowbase = m0 + w * 16 + quad * 4;
    float rs[4];
    #pragma unroll
    for (int reg = 0; reg < 4; ++reg) {
        int rw = rowbase + reg;
        rs[reg] = (rw < M) ? rsqrtf(cntf[rw] + 1.0f) : 0.f;   // dinv[row] pre-scale
    }
    #pragma unroll
    for (int nt = 0; nt < 8; ++nt) {
        int col = nt * 16 + mrow;
        #pragma unroll
        for (int reg = 0; reg < 4; ++reg) {
            int rw = rowbase + reg;
            if (rw < M) B16[(size_t)rw * HID + col] = f2bf_rne(acc[nt][reg] * rs[reg]);
        }
    }
}

// ---------------- fused final BN-finalize+apply + output projection ----------------
// h3 = relu(bf16(C)*sc+sh) + A16 (LDS only); out = h3 @ Wo + bo.
// Wo transposed into WoT[c][k]; inner product reads Hs and WoT as float4 ->
// 4x fewer LDS instructions. Accumulation order unchanged (k ascending, one acc).

__global__ void out_fused(const uint32* __restrict__ C16,  // [N][64]
                          const uint32* __restrict__ A16,  // [N][64]
                          const float* __restrict__ colsum_multi,
                          const float* __restrict__ gamma,
                          const float* __restrict__ beta,
                          const float* __restrict__ Wo,
                          const float* __restrict__ bo,
                          float* __restrict__ out) {
    __shared__ float Hs[64][132];          // pad 4
    __shared__ float WoT[OUT_DIM][132];    // transposed Wo, pad 4
    __shared__ float scs[128], shb[128];
    int tid = threadIdx.x;
    for (int i = tid; i < HID * OUT_DIM; i += 256) {
        int k = i / OUT_DIM;
        int c = i - k * OUT_DIM;
        WoT[c][k] = Wo[i];                 // coalesced Wo read
    }
    if (tid < 128) {
        float s = 0.f, q = 0.f;
        #pragma unroll
        for (int cc = 0; cc < 32; ++cc) {
            s += colsum_multi[cc * 256 + tid];
            q += colsum_multi[cc * 256 + tid + 128];
        }
        float mu = s * (1.0f / N_NODES);
        float var = q * (1.0f / N_NODES) - mu * mu;
        float rstd = rsqrtf(var + BN_EPS);
        float sc = rstd * gamma[tid];
        scs[tid] = sc;
        shb[tid] = beta[tid] - mu * sc;
    }
    __syncthreads();

    int n0 = blockIdx.x * 64;
    #pragma unroll
    for (int i = 0; i < 8; ++i) {
        int lin = i * 256 + tid;           // 0..2047
        int row = lin >> 5;                // 0..63
        int colq = lin & 31;               // 4-feature group
        int n = n0 + row;
        float4 h = make_float4(0.f, 0.f, 0.f, 0.f);
        if (n < N_NODES) {
            uint2 cv = ((const uint2*)C16)[(size_t)n * 32 + colq];
            uint2 av = ((const uint2*)A16)[(size_t)n * 32 + colq];
            float c0 = bf_lo(cv.x), c1 = bf_hi(cv.x), c2 = bf_lo(cv.y), c3 = bf_hi(cv.y);
            float4 s = *(const float4*)(scs + colq * 4);
            float4 t = *(const float4*)(shb + colq * 4);
            h.x = fmaxf(c0 * s.x + t.x, 0.f) + bf_lo(av.x);
            h.y = fmaxf(c1 * s.y + t.y, 0.f) + bf_hi(av.x);
            h.z = fmaxf(c2 * s.z + t.z, 0.f) + bf_lo(av.y);
            h.w = fmaxf(c3 * s.w + t.w, 0.f) + bf_hi(av.y);
        }
        *(float4*)&Hs[row][colq * 4] = h;
    }
    __syncthreads();

    #pragma unroll
    for (int j = 0; j < 3; ++j) {
        int o = j * 256 + tid;             // 0..639
        if (o < 64 * OUT_DIM) {
            int nl = o / OUT_DIM;
            int c = o - nl * OUT_DIM;
            int n = n0 + nl;
            if (n < N_NODES) {
                float s = 0.f;
                #pragma unroll 8
                for (int k = 0; k < HID; k += 4) {
                    float4 hv = *(const float4*)&Hs[nl][k];
                    float4 wv = *(const float4*)&WoT[c][k];
                    s += hv.x * wv.x;      // same order as scalar loop: bit-identical
                    s += hv.y * wv.y;
                    s += hv.z * wv.z;
                    s += hv.w * wv.w;
                }
                out[(size_t)n * OUT_DIM + c] = s + bo[c];
            }
        }
    }
}

// ---------------- launch ----------------

extern "C" void kernel_launch(void* const* d_in, const int* in_sizes, int n_in,
                              void* d_out, int out_size, void* d_ws, size_t ws_size,
                              hipStream_t stream) {
    const float* x     = (const float*)d_in[0];
    const int*   ei    = (const int*)d_in[1];
    const int*   src   = ei;
    const int*   dst   = ei + N_EDGES;
    const float* W_in  = (const float*)d_in[2];
    const float* b_in  = (const float*)d_in[3];
    const float* Wc    = (const float*)d_in[4];
    const float* bc    = (const float*)d_in[5];
    const float* gamma = (const float*)d_in[6];
    const float* beta  = (const float*)d_in[7];
    const float* W_out = (const float*)d_in[8];
    const float* b_out = (const float*)d_in[9];
    float* out = (float*)d_out;

    char* p = (char*)d_ws;
    auto alloc = [&](size_t bytes) -> char* {
        char* q = p;
        p += (bytes + 255) & ~(size_t)255;
        return q;
    };
    // zero span: cntf (200192B) + colsumAll (98304B) = 298496B
    float* cntf      = (float*)alloc(sizeof(float) * N_NODES);               // float edge counts
    float* colsumAll = (float*)alloc(sizeof(float) * 3 * 32 * 256);          // 32 hashed copies per layer
    unsigned short* A16 = (unsigned short*)alloc(sizeof(unsigned short) * N_NODES * HID); // residual h bf16
    unsigned short* B16 = (unsigned short*)alloc(sizeof(unsigned short) * N_NODES * HID); // messages bf16
    uint32* C16       = (uint32*)alloc(sizeof(unsigned short) * N_NODES * HID);           // aggregated bf16
    ushort_t* col     = (ushort_t*)alloc(sizeof(ushort_t) * N_NODES * CAP);  // bucketed src ids
    unsigned short* PWin = (unsigned short*)alloc(sizeof(unsigned short) * 4096 * 8);
    unsigned short* PWc  = (unsigned short*)alloc(sizeof(unsigned short) * 3 * 2048 * 8);

    const int gblk = (N_NODES + 63) / 64;   // 782

    // 1: zero (cntf+colsum) || pack all weights
    zero_pack_kernel<<<ZERO_BLK + 40, 256, 0, stream>>>((uint4*)cntf, W_in, Wc, PWin, PWc);

    // 2: bucket-fill || input GEMM (R6-proven single-stage), role-interleaved
    fill_gemm_in<<<FILL_BLK + gblk, 256, 0, stream>>>(src, dst, cntf, col,
                                                      x, PWin, PWc, b_in, B16, N_NODES);

    for (int l = 0; l < 3; ++l) {
        float* colsum = colsumAll + (size_t)l * 32 * 256;
        if (l == 0) {
            agg_stats_kernel<0><<<N_NODES / 4, dim3(64, 4), 0, stream>>>(
                (const uint32*)B16, cntf, col, bc + l * HID, C16, colsum);
        } else {
            agg_stats_kernel<1><<<N_NODES / 4, dim3(64, 4), 0, stream>>>(
                (const uint32*)B16, cntf, col, bc + l * HID, C16, colsum);
        }
        if (l == 0) {
            gemm_bn_fused<0><<<gblk, 256, 0, stream>>>(
                (const unsigned short*)C16, PWc + (size_t)1 * 2048 * 8, colsum,
                gamma, beta, cntf, A16, B16, N_NODES);
        } else if (l == 1) {
            gemm_bn_fused<1><<<gblk, 256, 0, stream>>>(
                (const unsigned short*)C16, PWc + (size_t)2 * 2048 * 8, colsum,
                gamma + HID, beta + HID, cntf, A16, B16, N_NODES);
        } else {
            out_fused<<<gblk, 256, 0, stream>>>(
                C16, (const uint32*)A16, colsum, gamma + 2 * HID, beta + 2 * HID, W_out, b_out, out);
        }
    }
}